// Round 1
// baseline (67.993 us; speedup 1.0000x reference)
//
#include <hip/hip_runtime.h>
#include <math.h>

#define H 256
#define W 256
#define TS 16

#if __has_builtin(__builtin_amdgcn_alignbyte)
__device__ __forceinline__ unsigned align_b(unsigned hi, unsigned lo, int sh) {
    return __builtin_amdgcn_alignbyte(hi, lo, sh);
}
#else
__device__ __forceinline__ unsigned align_b(unsigned hi, unsigned lo, int sh) {
    unsigned d;
    asm("v_alignbyte_b32 %0, %1, %2, %3" : "=v"(d) : "v"(hi), "v"(lo), "v"(sh));
    return d;
}
#endif

#if __has_builtin(__builtin_amdgcn_sad_u8)
__device__ __forceinline__ unsigned sad_u8(unsigned a, unsigned b, unsigned acc) {
    return __builtin_amdgcn_sad_u8(a, b, acc);
}
#else
__device__ __forceinline__ unsigned sad_u8(unsigned a, unsigned b, unsigned acc) {
    unsigned d;
    asm("v_sad_u8 %0, %1, %2, %3" : "=v"(d) : "v"(a), "v"(b), "v"(acc));
    return d;
}
#endif

// Binomial blur, exact same FP order as the previous (passing) kernel:
// vertical [1 2 1]/4 per column, then horizontal [1 2 1]/4.
__device__ __forceinline__ float binom3x3(const float* s, int r, int c, int stride) {
    float vm = (s[(r-1)*stride + (c-1)] + 2.0f*s[r*stride + (c-1)] + s[(r+1)*stride + (c-1)]) * 0.25f;
    float v0 = (s[(r-1)*stride + (c  )] + 2.0f*s[r*stride + (c  )] + s[(r+1)*stride + (c  )]) * 0.25f;
    float vp = (s[(r-1)*stride + (c+1)] + 2.0f*s[r*stride + (c+1)] + s[(r+1)*stride + (c+1)]) * 0.25f;
    return (vm + 2.0f*v0 + vp) * 0.25f;
}

__device__ __forceinline__ unsigned quant255(float v) {
    return (unsigned)fminf(fmaxf(rintf(v * 255.0f), 0.0f), 255.0f);
}

// Single fused kernel: binomial+quantize -> SAD search + subpixel (recomputed
// over a +/-3 halo so median+bilateral can run in the same block) -> 3x3
// median -> 5x5 bilateral. One 16x16 output tile per 256-thread block; all
// intermediates live in LDS (~22 KB).
//
// LDS region origins (relative to tile origin by0,bx0):
//   sf   : raw f, replicate-clamped, origin -10, 36x36
//   sg   : raw g, replicate-clamped, origin -6,  28x28
//   sfb  : binomial(f) float, zero for OOB, origin -9, 34 rows x 34 cols (stride 35)
//   sfq  : quantized binomial(f) bytes, zero OOB, origin -9, 34 rows x 36B (9 dwords)
//   sgq  : quantized binomial(g) bytes, zero OOB, origin -5, 26 rows x 28B (7 dwords)
//   sflow: flow at clamped pixel clamp(tile+[-3,+18]), 2 x 22x22
//   smed : 3x3 median of flow, zero OOB, origin -2, 2 x 20x20
__global__ void __launch_bounds__(256)
k_flow_fused(const float* __restrict__ f, const float* __restrict__ g,
             float* __restrict__ out) {
    __shared__ float    sf[36 * 36];
    __shared__ float    sg[28 * 28];
    __shared__ float    sfb[34 * 35];
    __shared__ unsigned sfq[34 * 9];
    __shared__ unsigned sgq[26 * 7];
    __shared__ float    sflow[2][22 * 22];
    __shared__ float    smed[2][20 * 20];

    int tx = threadIdx.x, ty = threadIdx.y;
    int bx0 = blockIdx.x * TS, by0 = blockIdx.y * TS;
    int tid = ty * TS + tx;

    // ---- P0: stage raw f, g (replicate clamp) ----
    for (int i = tid; i < 36 * 36; i += 256) {
        int r = i / 36, c = i % 36;
        int gy = min(max(by0 + r - 10, 0), H - 1);
        int gx = min(max(bx0 + c - 10, 0), W - 1);
        sf[i] = f[gy * W + gx];
    }
    for (int i = tid; i < 28 * 28; i += 256) {
        int r = i / 28, c = i % 28;
        int gy = min(max(by0 + r - 6, 0), H - 1);
        int gx = min(max(bx0 + c - 6, 0), W - 1);
        sg[i] = g[gy * W + gx];
    }
    __syncthreads();

    // ---- P1: binomial + quantize. fq dwords (306) also produce sfb floats;
    //          gq dwords (182). Each binomial value computed exactly once. ----
    for (int i = tid; i < 306 + 182; i += 256) {
        if (i < 306) {
            int row = i / 9, dw = i % 9;
            unsigned pack = 0;
            #pragma unroll
            for (int b = 0; b < 4; b++) {
                int col = dw * 4 + b;
                unsigned q = 0;
                if (col < 34) {
                    float bv = 0.0f;
                    int gy = by0 + row - 9, gx = bx0 + col - 9;
                    if (gy >= 0 && gy < H && gx >= 0 && gx < W) {
                        bv = binom3x3(sf, row + 1, col + 1, 36);
                        q = quant255(bv);
                    }
                    sfb[row * 35 + col] = bv;
                }
                pack |= q << (8 * b);
            }
            sfq[i] = pack;
        } else {
            int j = i - 306;
            int row = j / 7, dw = j % 7;
            unsigned pack = 0;
            #pragma unroll
            for (int b = 0; b < 4; b++) {
                int col = dw * 4 + b;
                unsigned q = 0;
                if (col < 26) {
                    int gy = by0 + row - 5, gx = bx0 + col - 5;
                    if (gy >= 0 && gy < H && gx >= 0 && gx < W)
                        q = quant255(binom3x3(sg, row + 1, col + 1, 28));
                }
                pack |= q << (8 * b);
            }
            sgq[j] = pack;
        }
    }
    __syncthreads();

    const unsigned char* sfq_b = (const unsigned char*)sfq;

    // Spiral rank, indexed (dy+3)*7+(dx+3); folds to immediates (full unroll).
    const unsigned RANKC[49] = {
        42,43,44,45,46,47,48,
        41,20,21,22,23,24,25,
        40,19, 6, 7, 8, 9,26,
        39,18, 5, 0, 1,10,27,
        38,17, 4, 3, 2,11,28,
        37,16,15,14,13,12,29,
        36,35,34,33,32,31,30
    };

    // ---- P2: SAD search + LK subpixel for all 22x22 (clamped-halo) flow
    //          pixels; 484 items over 256 threads. ----
    for (int it = tid; it < 22 * 22; it += 256) {
        int r = it / 22, c = it % 22;
        int py = min(max(by0 + r - 3, 0), H - 1);
        int px = min(max(bx0 + c - 3, 0), W - 1);
        int ro = py - by0 + 9, co = px - bx0 + 9;     // sfq/sfb coords
        int base = (co - 5) >> 2, a = (co - 5) & 3;

        // fq window: bytes [px-5 .. px+6] for rows [py-5 .. py+5]
        unsigned w0[11], w1[11], w2[11];
        #pragma unroll
        for (int r2 = 0; r2 < 11; r2++) {
            const unsigned* row = &sfq[(ro - 5 + r2) * 9 + base];
            unsigned d0 = row[0], d1 = row[1], d2 = row[2], d3 = row[3];
            w0[r2] = align_b(d1, d0, a);
            w1[r2] = align_b(d2, d1, a);
            w2[r2] = align_b(d3, d2, a);
        }

        // g template: row kh -> gq[py-2+kh][px-2 .. px+2]: 4 bytes + 1 byte
        int gro = py - by0 + 5, gco = px - bx0 + 5;   // sgq coords
        int gbase = (gco - 2) >> 2, ga = (gco - 2) & 3;
        unsigned gt_lo[5], gt_hi[5];
        #pragma unroll
        for (int kh = 0; kh < 5; kh++) {
            const unsigned* row = &sgq[(gro - 2 + kh) * 7 + gbase];
            unsigned d0 = row[0], d1 = row[1];
            gt_lo[kh] = align_b(d1, d0, ga);
            gt_hi[kh] = (d1 >> (8 * ga)) & 0xFFu;
        }

        unsigned best = 0xFFFFFFFFu;
        int bestd = 0;
        #pragma unroll
        for (int si = 0; si < 7; si++) {
            unsigned fd[11], f5[11];
            #pragma unroll
            for (int r2 = 0; r2 < 11; r2++) {
                fd[r2] = (si < 4) ? align_b(w1[r2], w0[r2], si) : align_b(w2[r2], w1[r2], si - 4);
                f5[r2] = (si < 4) ? ((w1[r2] >> (8 * si)) & 0xFFu)
                                  : ((w2[r2] >> (8 * (si - 4))) & 0xFFu);
            }
            #pragma unroll
            for (int sj = 0; sj < 7; sj++) {
                unsigned acc0 = 0, acc1 = 0;
                #pragma unroll
                for (int kh = 0; kh < 5; kh++) {
                    acc0 = sad_u8(fd[sj + kh], gt_lo[kh], acc0);
                    acc1 = sad_u8(f5[sj + kh], gt_hi[kh], acc1);
                }
                unsigned score = ((acc0 + acc1) << 6) + RANKC[sj * 7 + si];
                if (score < best) { best = score; bestd = sj * 7 + si; }
            }
        }
        int dy = bestd / 7 - 3, dx = bestd % 7 - 3;

        // Subpixel: 16-tap border ring; OOB taps contribute nothing (gradient
        // factor multiplies every term and comes from the zero-measure region).
        float aA = 0.f, bB = 0.f, dD = 0.f, pP = 0.f, qQ = 0.f;
        #pragma unroll
        for (int kh = 0; kh < 5; kh++) {
            #pragma unroll
            for (int kw = 0; kw < 5; kw++) {
                if (kh != 0 && kh != 4 && kw != 0 && kw != 4) continue;  // ring only
                int yy = py + kh - 2, xx = px + kw - 2;
                if (yy < 0 || yy >= H || xx < 0 || xx >= W) continue;
                int fy = yy - by0 + 9;
                int fx = xx - bx0 + 9;
                int xl = max(xx - 1, 0) - bx0 + 9, xr = min(xx + 1, W - 1) - bx0 + 9;
                int yu = max(yy - 1, 0) - by0 + 9, yd = min(yy + 1, H - 1) - by0 + 9;
                float gxv = (sfb[fy * 35 + xr] - sfb[fy * 35 + xl]) * 0.5f;
                float gyv = (sfb[yd * 35 + fx] - sfb[yu * 35 + fx]) * 0.5f;
                float fv = (float)sfq_b[(ro + dy + kh - 2) * 36 + (co + dx + kw - 2)] * (1.0f / 255.0f);
                float gv = (float)((kw < 4) ? ((gt_lo[kh] >> (8 * kw)) & 0xFFu) : gt_hi[kh]) * (1.0f / 255.0f);
                float z = gv - fv;
                aA += gxv * gxv;
                bB += gxv * gyv;
                dD += gyv * gyv;
                pP += z * gxv;
                qQ += z * gyv;
            }
        }
        float det = aA * dD - bB * bB;
        float u = dD * pP - bB * qQ;     // x
        float v = aA * qQ - bB * pP;     // y
        float suby = 0.f, subx = 0.f;
        if (det > 1e-7f) {
            suby = v / det;
            subx = u / det;
            if (fabsf(suby) >= 1.0f) suby = 0.f;
            if (fabsf(subx) >= 1.0f) subx = 0.f;
        }
        sflow[0][it] = (float)(-dy) + suby;
        sflow[1][it] = (float)(-dx) + subx;
    }
    __syncthreads();

    // ---- P3: 3x3 median (replicate clamp), zero for OOB pixels ----
    for (int i = tid; i < 2 * 20 * 20; i += 256) {
        int ch = i / 400, rem = i % 400;
        int rm = rem / 20, cm = rem % 20;
        int my = by0 + rm - 2, mx = bx0 + cm - 2;
        float m = 0.0f;
        if (my >= 0 && my < H && mx >= 0 && mx < W) {
            float v[9];
            int n = 0;
            #pragma unroll
            for (int dj = -1; dj <= 1; dj++) {
                #pragma unroll
                for (int di = -1; di <= 1; di++) {
                    int fr = min(max(my + dj, 0), H - 1) - by0 + 3;
                    int fc = min(max(mx + di, 0), W - 1) - bx0 + 3;
                    v[n++] = sflow[ch][fr * 22 + fc];
                }
            }
#define MSWAP(A, B) { float t_ = fminf(v[A], v[B]); v[B] = fmaxf(v[A], v[B]); v[A] = t_; }
            MSWAP(1,2); MSWAP(4,5); MSWAP(7,8);
            MSWAP(0,1); MSWAP(3,4); MSWAP(6,7);
            MSWAP(1,2); MSWAP(4,5); MSWAP(7,8);
            MSWAP(0,3); MSWAP(5,8); MSWAP(4,7);
            MSWAP(3,6); MSWAP(1,4); MSWAP(2,5);
            MSWAP(4,7); MSWAP(4,2); MSWAP(6,4);
            MSWAP(4,2);
#undef MSWAP
            m = v[4];
        }
        smed[ch][i % 400] = m;
    }
    __syncthreads();

    // ---- P4: 5x5 bilateral (zero pad via zero-OOB sfb/smed) ----
    int x = bx0 + tx, y = by0 + ty;
    const float kern = -0.22222222222222221f;   // -1/(2*1.5^2)
    const float sii  = 200.0f;                  // 1/(2*0.05^2)
    float cp = sfb[(ty + 9) * 35 + (tx + 9)];
    float sc = 0.f, sy = 0.f, sx = 0.f;
    #pragma unroll
    for (int j = 0; j < 5; j++) {
        #pragma unroll
        for (int i = 0; i < 5; i++) {
            float ck = sfb[(ty + 7 + j) * 35 + (tx + 7 + i)];
            float df = cp - ck;
            float coeff = 1.0f - fabsf(kern - df * df * sii);
            coeff = fminf(fmaxf(coeff, 0.0f), 1.0f);
            int s = (ty + j) * 20 + (tx + i);
            sc += coeff;
            sy += coeff * smed[0][s];
            sx += coeff * smed[1][s];
        }
    }
    out[y * W + x]         = sy / sc;
    out[H * W + y * W + x] = sx / sc;
}

extern "C" void kernel_launch(void* const* d_in, const int* in_sizes, int n_in,
                              void* d_out, int out_size, void* d_ws, size_t ws_size,
                              hipStream_t stream) {
    const float* f = (const float*)d_in[0];
    const float* g = (const float*)d_in[1];
    float* out = (float*)d_out;
    (void)d_ws; (void)ws_size;

    dim3 blk(TS, TS);
    dim3 grd(W / TS, H / TS);
    k_flow_fused<<<grd, blk, 0, stream>>>(f, g, out);
}

// Round 2
// 67.686 us; speedup vs baseline: 1.0045x; 1.0045x over previous
//
#include <hip/hip_runtime.h>
#include <math.h>

#define H 256
#define W 256
#define TS 16

#if __has_builtin(__builtin_amdgcn_alignbyte)
__device__ __forceinline__ unsigned align_b(unsigned hi, unsigned lo, int sh) {
    return __builtin_amdgcn_alignbyte(hi, lo, sh);
}
#else
__device__ __forceinline__ unsigned align_b(unsigned hi, unsigned lo, int sh) {
    unsigned d;
    asm("v_alignbyte_b32 %0, %1, %2, %3" : "=v"(d) : "v"(hi), "v"(lo), "v"(sh));
    return d;
}
#endif

#if __has_builtin(__builtin_amdgcn_sad_u8)
__device__ __forceinline__ unsigned sad_u8(unsigned a, unsigned b, unsigned acc) {
    return __builtin_amdgcn_sad_u8(a, b, acc);
}
#else
__device__ __forceinline__ unsigned sad_u8(unsigned a, unsigned b, unsigned acc) {
    unsigned d;
    asm("v_sad_u8 %0, %1, %2, %3" : "=v"(d) : "v"(a), "v"(b), "v"(acc));
    return d;
}
#endif

// Binomial blur, exact same FP order as the previous (passing) kernel:
// vertical [1 2 1]/4 per column, then horizontal [1 2 1]/4.
__device__ __forceinline__ float binom3x3(const float* s, int r, int c, int stride) {
    float vm = (s[(r-1)*stride + (c-1)] + 2.0f*s[r*stride + (c-1)] + s[(r+1)*stride + (c-1)]) * 0.25f;
    float v0 = (s[(r-1)*stride + (c  )] + 2.0f*s[r*stride + (c  )] + s[(r+1)*stride + (c  )]) * 0.25f;
    float vp = (s[(r-1)*stride + (c+1)] + 2.0f*s[r*stride + (c+1)] + s[(r+1)*stride + (c+1)]) * 0.25f;
    return (vm + 2.0f*v0 + vp) * 0.25f;
}

__device__ __forceinline__ unsigned quant255(float v) {
    return (unsigned)fminf(fmaxf(rintf(v * 255.0f), 0.0f), 255.0f);
}

// Single fused kernel, 512 threads/block (2 waves/SIMD at 1 block/CU).
// P2 (SAD search) is split 2-threads-per-item: lane half 0 scans si 0..3
// (window bytes 0..7), half 1 scans si 4..6 (bytes 4..11); pair-combined via
// __shfl_xor(.,1) on the packed lexicographic score. Subpixel runs on both
// lanes (identical), half 0 writes.
//
// LDS region origins (relative to tile origin by0,bx0):
//   sf   : raw f, replicate-clamped, origin -10, 36x36
//   sg   : raw g, replicate-clamped, origin -6,  28x28
//   sfb  : binomial(f) float, zero for OOB, origin -9, 34 rows x 34 cols (stride 35)
//   sfq  : quantized binomial(f) bytes, zero OOB, origin -9, 34 rows x 36B (9 dwords)
//   sgq  : quantized binomial(g) bytes, zero OOB, origin -5, 26 rows x 28B (7 dwords)
//   sflow: flow at clamped pixel clamp(tile+[-3,+18]), 2 x 22x22
//   smed : 3x3 median of flow, zero OOB, origin -2, 2 x 20x20
__global__ void __launch_bounds__(512)
k_flow_fused(const float* __restrict__ f, const float* __restrict__ g,
             float* __restrict__ out) {
    __shared__ float    sf[36 * 36];
    __shared__ float    sg[28 * 28];
    __shared__ float    sfb[34 * 35];
    __shared__ unsigned sfq[34 * 9];
    __shared__ unsigned sgq[26 * 7];
    __shared__ float    sflow[2][22 * 22];
    __shared__ float    smed[2][20 * 20];

    int bx0 = blockIdx.x * TS, by0 = blockIdx.y * TS;
    int tid = threadIdx.x;

    // ---- P0: stage raw f, g (replicate clamp) ----
    for (int i = tid; i < 36 * 36; i += 512) {
        int r = i / 36, c = i % 36;
        int gy = min(max(by0 + r - 10, 0), H - 1);
        int gx = min(max(bx0 + c - 10, 0), W - 1);
        sf[i] = f[gy * W + gx];
    }
    for (int i = tid; i < 28 * 28; i += 512) {
        int r = i / 28, c = i % 28;
        int gy = min(max(by0 + r - 6, 0), H - 1);
        int gx = min(max(bx0 + c - 6, 0), W - 1);
        sg[i] = g[gy * W + gx];
    }
    __syncthreads();

    // ---- P1: binomial + quantize (306 fq dwords + 182 gq dwords, 1 pass) ----
    if (tid < 306 + 182) {
        int i = tid;
        if (i < 306) {
            int row = i / 9, dw = i % 9;
            unsigned pack = 0;
            #pragma unroll
            for (int b = 0; b < 4; b++) {
                int col = dw * 4 + b;
                unsigned q = 0;
                if (col < 34) {
                    float bv = 0.0f;
                    int gy = by0 + row - 9, gx = bx0 + col - 9;
                    if (gy >= 0 && gy < H && gx >= 0 && gx < W) {
                        bv = binom3x3(sf, row + 1, col + 1, 36);
                        q = quant255(bv);
                    }
                    sfb[row * 35 + col] = bv;
                }
                pack |= q << (8 * b);
            }
            sfq[i] = pack;
        } else {
            int j = i - 306;
            int row = j / 7, dw = j % 7;
            unsigned pack = 0;
            #pragma unroll
            for (int b = 0; b < 4; b++) {
                int col = dw * 4 + b;
                unsigned q = 0;
                if (col < 26) {
                    int gy = by0 + row - 5, gx = bx0 + col - 5;
                    if (gy >= 0 && gy < H && gx >= 0 && gx < W)
                        q = quant255(binom3x3(sg, row + 1, col + 1, 28));
                }
                pack |= q << (8 * b);
            }
            sgq[j] = pack;
        }
    }
    __syncthreads();

    const unsigned char* sfq_b = (const unsigned char*)sfq;

    // Spiral rank, indexed (dy+3)*7+(dx+3); compile-time indices only.
    const unsigned RANKC[49] = {
        42,43,44,45,46,47,48,
        41,20,21,22,23,24,25,
        40,19, 6, 7, 8, 9,26,
        39,18, 5, 0, 1,10,27,
        38,17, 4, 3, 2,11,28,
        37,16,15,14,13,12,29,
        36,35,34,33,32,31,30
    };

    // ---- P2: SAD search (pair-split) + LK subpixel for all 22x22 items.
    //          968 half-items over 512 threads. ----
    for (int u = tid; u < 2 * 22 * 22; u += 512) {
        int it = u >> 1, half = u & 1;
        int r = it / 22, c = it % 22;
        int py = min(max(by0 + r - 3, 0), H - 1);
        int px = min(max(bx0 + c - 3, 0), W - 1);
        int ro = py - by0 + 9, co = px - bx0 + 9;     // sfq/sfb coords
        int base = (co - 5) >> 2, a = (co - 5) & 3;

        // Half-window: half 0 covers fq bytes [px-5 .. px+2] (si 0..3),
        //              half 1 covers fq bytes [px-1 .. px+6] (si 4..6).
        unsigned wA[11], wB[11];
        #pragma unroll
        for (int r2 = 0; r2 < 11; r2++) {
            const unsigned* row = &sfq[(ro - 5 + r2) * 9 + base + half];
            unsigned dA = row[0], dB = row[1], dC = row[2];
            wA[r2] = align_b(dB, dA, a);
            wB[r2] = align_b(dC, dB, a);
        }

        // g template: row kh -> gq[py-2+kh][px-2 .. px+2]: 4 bytes + 1 byte
        int gro = py - by0 + 5, gco = px - bx0 + 5;   // sgq coords
        int gbase = (gco - 2) >> 2, ga = (gco - 2) & 3;
        unsigned gt_lo[5], gt_hi[5];
        #pragma unroll
        for (int kh = 0; kh < 5; kh++) {
            const unsigned* row = &sgq[(gro - 2 + kh) * 7 + gbase];
            unsigned d0 = row[0], d1 = row[1];
            gt_lo[kh] = align_b(d1, d0, ga);
            gt_hi[kh] = (d1 >> (8 * ga)) & 0xFFu;
        }

        unsigned best = 0xFFFFFFFFu;
        int bestd = 0;
        #pragma unroll
        for (int sl = 0; sl < 4; sl++) {
            if (!(sl == 3 && half)) {           // half 1 scans only sl 0..2
                unsigned fd[11], f5[11];
                #pragma unroll
                for (int r2 = 0; r2 < 11; r2++) {
                    fd[r2] = align_b(wB[r2], wA[r2], sl);
                    f5[r2] = (wB[r2] >> (8 * sl)) & 0xFFu;
                }
                #pragma unroll
                for (int sj = 0; sj < 7; sj++) {
                    unsigned acc0 = 0, acc1 = 0;
                    #pragma unroll
                    for (int kh = 0; kh < 5; kh++) {
                        acc0 = sad_u8(fd[sj + kh], gt_lo[kh], acc0);
                        acc1 = sad_u8(f5[sj + kh], gt_hi[kh], acc1);
                    }
                    int i0 = sj * 7 + sl;
                    int i1 = sj * 7 + 4 + sl; if (i1 > 48) i1 = 48;  // masked-out path
                    unsigned rk = half ? RANKC[i1] : RANKC[i0];
                    unsigned score = ((acc0 + acc1) << 6) + rk;
                    int dsp = sj * 7 + sl + (half << 2);
                    if (score < best) { best = score; bestd = dsp; }
                }
            }
        }
        // Pair combine (ranks unique -> no ties possible).
        unsigned obest = __shfl_xor(best, 1);
        int obestd = __shfl_xor(bestd, 1);
        if (obest < best) { best = obest; bestd = obestd; }
        int dy = bestd / 7 - 3, dx = bestd % 7 - 3;

        // Subpixel: 16-tap border ring (both lanes compute identically);
        // OOB taps contribute nothing.
        float aA = 0.f, bB = 0.f, dD = 0.f, pP = 0.f, qQ = 0.f;
        #pragma unroll
        for (int kh = 0; kh < 5; kh++) {
            #pragma unroll
            for (int kw = 0; kw < 5; kw++) {
                if (kh != 0 && kh != 4 && kw != 0 && kw != 4) continue;  // ring only
                int yy = py + kh - 2, xx = px + kw - 2;
                if (yy < 0 || yy >= H || xx < 0 || xx >= W) continue;
                int fy = yy - by0 + 9;
                int fx = xx - bx0 + 9;
                int xl = max(xx - 1, 0) - bx0 + 9, xr = min(xx + 1, W - 1) - bx0 + 9;
                int yu = max(yy - 1, 0) - by0 + 9, yd = min(yy + 1, H - 1) - by0 + 9;
                float gxv = (sfb[fy * 35 + xr] - sfb[fy * 35 + xl]) * 0.5f;
                float gyv = (sfb[yd * 35 + fx] - sfb[yu * 35 + fx]) * 0.5f;
                float fv = (float)sfq_b[(ro + dy + kh - 2) * 36 + (co + dx + kw - 2)] * (1.0f / 255.0f);
                float gv = (float)((kw < 4) ? ((gt_lo[kh] >> (8 * kw)) & 0xFFu) : gt_hi[kh]) * (1.0f / 255.0f);
                float z = gv - fv;
                aA += gxv * gxv;
                bB += gxv * gyv;
                dD += gyv * gyv;
                pP += z * gxv;
                qQ += z * gyv;
            }
        }
        float det = aA * dD - bB * bB;
        float u2 = dD * pP - bB * qQ;     // x
        float v2 = aA * qQ - bB * pP;     // y
        float suby = 0.f, subx = 0.f;
        if (det > 1e-7f) {
            suby = v2 / det;
            subx = u2 / det;
            if (fabsf(suby) >= 1.0f) suby = 0.f;
            if (fabsf(subx) >= 1.0f) subx = 0.f;
        }
        if (!half) {
            sflow[0][it] = (float)(-dy) + suby;
            sflow[1][it] = (float)(-dx) + subx;
        }
    }
    __syncthreads();

    // ---- P3: 3x3 median (replicate clamp), zero for OOB pixels ----
    for (int i = tid; i < 2 * 20 * 20; i += 512) {
        int ch = i / 400, rem = i % 400;
        int rm = rem / 20, cm = rem % 20;
        int my = by0 + rm - 2, mx = bx0 + cm - 2;
        float m = 0.0f;
        if (my >= 0 && my < H && mx >= 0 && mx < W) {
            float v[9];
            int n = 0;
            #pragma unroll
            for (int dj = -1; dj <= 1; dj++) {
                #pragma unroll
                for (int di = -1; di <= 1; di++) {
                    int fr = min(max(my + dj, 0), H - 1) - by0 + 3;
                    int fc = min(max(mx + di, 0), W - 1) - bx0 + 3;
                    v[n++] = sflow[ch][fr * 22 + fc];
                }
            }
#define MSWAP(A, B) { float t_ = fminf(v[A], v[B]); v[B] = fmaxf(v[A], v[B]); v[A] = t_; }
            MSWAP(1,2); MSWAP(4,5); MSWAP(7,8);
            MSWAP(0,1); MSWAP(3,4); MSWAP(6,7);
            MSWAP(1,2); MSWAP(4,5); MSWAP(7,8);
            MSWAP(0,3); MSWAP(5,8); MSWAP(4,7);
            MSWAP(3,6); MSWAP(1,4); MSWAP(2,5);
            MSWAP(4,7); MSWAP(4,2); MSWAP(6,4);
            MSWAP(4,2);
#undef MSWAP
            m = v[4];
        }
        smed[ch][rem] = m;
    }
    __syncthreads();

    // ---- P4: 5x5 bilateral (zero pad via zero-OOB sfb/smed).
    //          512 items = 256 pixels x 2 channels, one per thread. ----
    {
        int ch = tid >> 8, pix = tid & 255;
        int tx = pix & 15, ty = pix >> 4;
        int x = bx0 + tx, y = by0 + ty;
        const float kern = -0.22222222222222221f;   // -1/(2*1.5^2)
        const float sii  = 200.0f;                  // 1/(2*0.05^2)
        float cp = sfb[(ty + 9) * 35 + (tx + 9)];
        float sc = 0.f, sv = 0.f;
        #pragma unroll
        for (int j = 0; j < 5; j++) {
            #pragma unroll
            for (int i = 0; i < 5; i++) {
                float ck = sfb[(ty + 7 + j) * 35 + (tx + 7 + i)];
                float df = cp - ck;
                float coeff = 1.0f - fabsf(kern - df * df * sii);
                coeff = fminf(fmaxf(coeff, 0.0f), 1.0f);
                sc += coeff;
                sv += coeff * smed[ch][(ty + j) * 20 + (tx + i)];
            }
        }
        out[ch * H * W + y * W + x] = sv / sc;
    }
}

extern "C" void kernel_launch(void* const* d_in, const int* in_sizes, int n_in,
                              void* d_out, int out_size, void* d_ws, size_t ws_size,
                              hipStream_t stream) {
    const float* f = (const float*)d_in[0];
    const float* g = (const float*)d_in[1];
    float* out = (float*)d_out;
    (void)d_ws; (void)ws_size;

    dim3 blk(512);
    dim3 grd(W / TS, H / TS);
    k_flow_fused<<<grd, blk, 0, stream>>>(f, g, out);
}